// Round 9
// baseline (931.115 us; speedup 1.0000x reference)
//
#include <hip/hip_runtime.h>

#define B_ 8
#define N_ 2048

#define REP8(M) M(0) M(1) M(2) M(3) M(4) M(5) M(6) M(7)

// one DPP max step: lanes without a source contribute -1.0f (identity; dists >= 0)
template <int CTRL>
__device__ __forceinline__ float dppMaxStep(float v) {
  int o = __builtin_amdgcn_update_dpp(__float_as_int(-1.0f), __float_as_int(v),
                                      CTRL, 0xF, 0xF, false);
  return fmaxf(v, __int_as_float(o));
}

__device__ __forceinline__ float waveMax(float v) {
  v = dppMaxStep<0x111>(v);  // row_shr:1
  v = dppMaxStep<0x112>(v);  // row_shr:2
  v = dppMaxStep<0x114>(v);  // row_shr:4
  v = dppMaxStep<0x118>(v);  // row_shr:8
  v = dppMaxStep<0x142>(v);  // row_bcast:15
  v = dppMaxStep<0x143>(v);  // row_bcast:31  -> lane 63 holds wave max
  return v;
}

#define DECL8(i) float X##i, Y##i, Z##i, D##i;

// distance update: bit-exact ((dx*dx+dy*dy)+dz*dz), fminf
#define UPD8(i)                                                               \
  {                                                                           \
    float ddx = __fsub_rn(X##i, qx);                                          \
    float ddy = __fsub_rn(Y##i, qy);                                          \
    float ddz = __fsub_rn(Z##i, qz);                                          \
    float d = __fadd_rn(__fadd_rn(__fmul_rn(ddx, ddx), __fmul_rn(ddy, ddy)),  \
                        __fmul_rn(ddz, ddz));                                 \
    D##i = fminf(D##i, d);                                                    \
  }

// in-lane argmax tree; strict > in ascending order keeps smallest index on tie
#define LANE_TREE8V                                                           \
  float v01 = (D1 > D0) ? D1 : D0;  int g01 = (D1 > D0) ? 1 : 0;              \
  float v23 = (D3 > D2) ? D3 : D2;  int g23 = (D3 > D2) ? 3 : 2;              \
  float v45 = (D5 > D4) ? D5 : D4;  int g45 = (D5 > D4) ? 5 : 4;              \
  float v67 = (D7 > D6) ? D7 : D6;  int g67 = (D7 > D6) ? 7 : 6;              \
  float v03 = (v23 > v01) ? v23 : v01;  int g03 = (v23 > v01) ? g23 : g01;    \
  float v47 = (v67 > v45) ? v67 : v45;  int g47 = (v67 > v45) ? g67 : g45;    \
  float bv  = (v47 > v03) ? v47 : v03;  int bg  = (v47 > v03) ? g47 : g03;

// owner-lane coordinate mux from the 8 register-resident points (bg = local j 0..7)
#define OWNER_MUX                                                             \
  bool j1 = bg & 1, j2 = bg & 2, j4 = bg & 4;                                 \
  float xl = j2 ? (j1 ? X3 : X2) : (j1 ? X1 : X0);                            \
  float xh = j2 ? (j1 ? X7 : X6) : (j1 ? X5 : X4);                            \
  float yl = j2 ? (j1 ? Y3 : Y2) : (j1 ? Y1 : Y0);                            \
  float yh = j2 ? (j1 ? Y7 : Y6) : (j1 ? Y5 : Y4);                            \
  float zl = j2 ? (j1 ? Z3 : Z2) : (j1 ? Z1 : Z0);                            \
  float zh = j2 ? (j1 ? Z7 : Z6) : (j1 ? Z5 : Z4);                            \
  float wx = j4 ? xh : xl, wy = j4 ? yh : yl, wz = j4 ? zh : zl;

// ---------------- fused normalize (f64 stats, fp32 ops match np) + FPS 2048->1024 ----------------
// R8 loop with owner-coord slots: the unique owner lane (lowest tying lane = smallest index,
// jnp.argmax semantics) writes (vmax, x, y, z) to its wave slot; the dependent Sp[fg] LDS
// lookup and the second readlane hop are gone. Cross-wave tie-break: strict > keeps the
// earlier wave = smaller global indices. Selections bit-identical to all passing rounds.
__global__ __launch_bounds__(256) void norm_fps1_kernel(const float* __restrict__ pos,
                                                        float* __restrict__ pos1) {
  __shared__ float4 Sp[2048];     // normalized points (q0 source; keeps LDS footprint = R8)
  __shared__ float outP[1024 * 3];// selected points, flushed at end
  __shared__ float4 red[2][4];    // double-buffered per-wave (vmax, x, y, z) slots
  __shared__ double wsum[3][4];
  __shared__ float bc[6];
  const int b = blockIdx.x, tid = threadIdx.x;
  const float* base = pos + (size_t)b * N_ * 3;
  float px[8], py[8], pz[8];
  double sx = 0.0, sy = 0.0, sz = 0.0;
#pragma unroll
  for (int k = 0; k < 8; ++k) {
    int g = tid * 8 + k;
    px[k] = base[g * 3 + 0];
    py[k] = base[g * 3 + 1];
    pz[k] = base[g * 3 + 2];
    sx += (double)px[k]; sy += (double)py[k]; sz += (double)pz[k];
  }
  const int wid = tid >> 6, lid = tid & 63;
#pragma unroll
  for (int off = 32; off >= 1; off >>= 1) {
    sx += __shfl_down(sx, off);
    sy += __shfl_down(sy, off);
    sz += __shfl_down(sz, off);
  }
  if (lid == 0) { wsum[0][wid] = sx; wsum[1][wid] = sy; wsum[2][wid] = sz; }
  __syncthreads();
  if (tid == 0) {
    bc[0] = (float)((wsum[0][0] + wsum[0][1] + wsum[0][2] + wsum[0][3]) / 2048.0);
    bc[1] = (float)((wsum[1][0] + wsum[1][1] + wsum[1][2] + wsum[1][3]) / 2048.0);
    bc[2] = (float)((wsum[2][0] + wsum[2][1] + wsum[2][2] + wsum[2][3]) / 2048.0);
  }
  __syncthreads();
  const float mx = bc[0], my = bc[1], mz = bc[2];
  float dxa[8], dya[8], dza[8];
  double qxs = 0.0, qys = 0.0, qzs = 0.0;
#pragma unroll
  for (int k = 0; k < 8; ++k) {
    dxa[k] = __fsub_rn(px[k], mx);
    dya[k] = __fsub_rn(py[k], my);
    dza[k] = __fsub_rn(pz[k], mz);
    qxs += (double)__fmul_rn(dxa[k], dxa[k]);
    qys += (double)__fmul_rn(dya[k], dya[k]);
    qzs += (double)__fmul_rn(dza[k], dza[k]);
  }
#pragma unroll
  for (int off = 32; off >= 1; off >>= 1) {
    qxs += __shfl_down(qxs, off);
    qys += __shfl_down(qys, off);
    qzs += __shfl_down(qzs, off);
  }
  if (lid == 0) { wsum[0][wid] = qxs; wsum[1][wid] = qys; wsum[2][wid] = qzs; }
  __syncthreads();
  if (tid == 0) {
    bc[3] = __fadd_rn(__fsqrt_rn((float)((wsum[0][0]+wsum[0][1]+wsum[0][2]+wsum[0][3]) / 2047.0)), 1e-6f);
    bc[4] = __fadd_rn(__fsqrt_rn((float)((wsum[1][0]+wsum[1][1]+wsum[1][2]+wsum[1][3]) / 2047.0)), 1e-6f);
    bc[5] = __fadd_rn(__fsqrt_rn((float)((wsum[2][0]+wsum[2][1]+wsum[2][2]+wsum[2][3]) / 2047.0)), 1e-6f);
  }
  __syncthreads();
  const float isx = bc[3], isy = bc[4], isz = bc[5];
  REP8(DECL8)
#define INIT8(i)                                                              \
  {                                                                           \
    X##i = __fdiv_rn(dxa[i], isx);                                            \
    Y##i = __fdiv_rn(dya[i], isy);                                            \
    Z##i = __fdiv_rn(dza[i], isz);                                            \
    D##i = 1e10f;                                                             \
    Sp[tid * 8 + i] = make_float4(X##i, Y##i, Z##i, 0.0f);                    \
  }
  REP8(INIT8)
  __syncthreads();
  float4 q0 = Sp[0];  // deterministic FPS start at index 0 (LDS broadcast)
  float qx = q0.x, qy = q0.y, qz = q0.z;
  if (tid == 0) { outP[0] = qx; outP[1] = qy; outP[2] = qz; }
  for (int t = 1; t < 1024; ++t) {
    REP8(UPD8)
    LANE_TREE8V
    float mv = waveMax(bv);
    float vmax = __int_as_float(__builtin_amdgcn_readlane(__float_as_int(mv), 63));
    unsigned long long msk = __ballot(bv == vmax);
    int owner = __builtin_ctzll(msk);       // lowest tying lane = smallest global index
    OWNER_MUX                               // issues in parallel with the DPP chain
    const int par = t & 1;
    if (lid == owner) red[par][wid] = make_float4(vmax, wx, wy, wz);
    __syncthreads();
    float4 s0 = red[par][0], s1 = red[par][1], s2 = red[par][2], s3 = red[par][3];
    float fv = s0.x, fx = s0.y, fy = s0.z, fz = s0.w;
    if (s1.x > fv) { fv = s1.x; fx = s1.y; fy = s1.z; fz = s1.w; }
    if (s2.x > fv) { fv = s2.x; fx = s2.y; fy = s2.z; fz = s2.w; }
    if (s3.x > fv) { fv = s3.x; fx = s3.y; fy = s3.z; fz = s3.w; }
    qx = fx; qy = fy; qz = fz;
    if (tid == 0) { outP[t * 3 + 0] = qx; outP[t * 3 + 1] = qy; outP[t * 3 + 2] = qz; }
  }
  __syncthreads();
  float* p1b = pos1 + (size_t)b * 1024 * 3;
  for (int i = tid; i < 3072; i += 256) p1b[i] = outP[i];
}

// ---------------- mid: fps2 (blocks 0..7, starts first) + conv1 (blocks 8..8199) ----------------
__global__ __launch_bounds__(128) void mid_kernel(
    const float* __restrict__ pos1,
    const float* __restrict__ w1, const float* __restrict__ b1,
    const float* __restrict__ g, const float* __restrict__ beta,
    const float* __restrict__ m, const float* __restrict__ v,
    const float* __restrict__ w2, const float* __restrict__ b2,
    float* __restrict__ x1out,
    int* __restrict__ idx2, float* __restrict__ pos2) {
  __shared__ union MidU {
    struct { int nbr[64]; int cnt; float hbuf[128]; } c;
    struct { float4 Sp2[1024]; float4 red2[2][2]; int idxS[2][2];
             float outP[512 * 3]; int outI[512]; } f;
  } u;
  if (blockIdx.x >= 8) {
    // ---- conv1: one block per target point, sparse neighbor scan ----
    const int bb = blockIdx.x - 8;
    const int b = bb >> 10;
    const int i = bb & 1023;
    const int c = threadIdx.x;
    const float* pb = pos1 + (size_t)b * 1024 * 3;
    const float xi = pb[i * 3 + 0], yi = pb[i * 3 + 1], zi = pb[i * 3 + 2];
    if (c == 0) u.c.cnt = 0;
    __syncthreads();
    const float rr = (float)(0.1 * 0.1);  // matches weak-typed r*r rounding
#pragma unroll
    for (int k = 0; k < 8; ++k) {
      int j = c + (k << 7);
      float ddx = __fsub_rn(xi, pb[j * 3 + 0]);
      float ddy = __fsub_rn(yi, pb[j * 3 + 1]);
      float ddz = __fsub_rn(zi, pb[j * 3 + 2]);
      float d2 = __fadd_rn(__fadd_rn(__fmul_rn(ddx, ddx), __fmul_rn(ddy, ddy)),
                           __fmul_rn(ddz, ddz));
      if (d2 <= rr) {
        int s = atomicAdd(&u.c.cnt, 1);
        if (s < 64) u.c.nbr[s] = j;
      }
    }
    __syncthreads();
    const int n = min(u.c.cnt, 64);
    const float scale = g[c] / sqrtf(v[c] + 1e-5f);
    const float shift = beta[c] - m[c] * scale;
    float w1c[6];
#pragma unroll
    for (int f = 0; f < 6; ++f) w1c[f] = w1[f * 128 + c];
    const float b1c = b1[c], b2c = b2[c];
    float acc = 0.0f;  // relu >= 0 and self always valid
    for (int qq = 0; qq < n; ++qq) {
      const int j = u.c.nbr[qq];
      const float fx = pb[j * 3 + 0], fy = pb[j * 3 + 1], fz = pb[j * 3 + 2];
      float h = b1c;
      h = fmaf(fx, w1c[0], h);
      h = fmaf(fy, w1c[1], h);
      h = fmaf(fz, w1c[2], h);
      h = fmaf(fx - xi, w1c[3], h);
      h = fmaf(fy - yi, w1c[4], h);
      h = fmaf(fz - zi, w1c[5], h);
      h = fmaxf(fmaf(h, scale, shift), 0.0f);
      u.c.hbuf[c] = h;
      __syncthreads();
      float o = b2c;
#pragma unroll 8
      for (int k2 = 0; k2 < 128; ++k2) o = fmaf(u.c.hbuf[k2], w2[(k2 << 7) + c], o);
      acc = fmaxf(acc, fmaxf(o, 0.0f));
      __syncthreads();
    }
    x1out[((size_t)(b * 1024 + i)) * 128 + c] = acc;
  } else {
    // ---- fps2: 1024 -> 512, 2 waves, 8 pts/thread in scalars, owner-coord slots ----
    const int b = blockIdx.x;
    const int tid = threadIdx.x;
    const int wid = tid >> 6, lid = tid & 63;
    const float* p1b = pos1 + (size_t)b * 1024 * 3;
    REP8(DECL8)
#define LOADF2(i)                                                             \
    {                                                                         \
      const float* pp = p1b + (tid * 8 + i) * 3;                              \
      X##i = pp[0]; Y##i = pp[1]; Z##i = pp[2];                               \
      D##i = 1e10f;                                                           \
      u.f.Sp2[tid * 8 + i] = make_float4(X##i, Y##i, Z##i, 0.0f);             \
    }
    REP8(LOADF2)
    __syncthreads();
    float4 q0 = u.f.Sp2[0];
    float qx = q0.x, qy = q0.y, qz = q0.z;
    if (tid == 0) {
      u.f.outP[0] = qx; u.f.outP[1] = qy; u.f.outP[2] = qz;
      u.f.outI[0] = 0;
    }
    const int gbase = tid * 8;
    for (int t = 1; t < 512; ++t) {
      REP8(UPD8)
      LANE_TREE8V
      float mv = waveMax(bv);
      float vmax = __int_as_float(__builtin_amdgcn_readlane(__float_as_int(mv), 63));
      unsigned long long msk = __ballot(bv == vmax);
      int owner = __builtin_ctzll(msk);
      OWNER_MUX
      const int par = t & 1;
      if (lid == owner) {
        u.f.red2[par][wid] = make_float4(vmax, wx, wy, wz);
        u.f.idxS[par][wid] = gbase + bg;   // owner's global index (idx2 output)
      }
      __syncthreads();
      float4 s0 = u.f.red2[par][0], s1 = u.f.red2[par][1];
      int i0 = u.f.idxS[par][0], i1 = u.f.idxS[par][1];
      bool p = s1.x > s0.x;   // strict >: wave 0 (smaller indices) wins ties
      qx = p ? s1.y : s0.y;
      qy = p ? s1.z : s0.z;
      qz = p ? s1.w : s0.w;
      int fg = p ? i1 : i0;
      if (tid == 0) {
        u.f.outP[t * 3 + 0] = qx; u.f.outP[t * 3 + 1] = qy; u.f.outP[t * 3 + 2] = qz;
        u.f.outI[t] = fg;
      }
    }
    __syncthreads();
    float* p2b = pos2 + (size_t)b * 512 * 3;
    int* i2b = idx2 + b * 512;
    for (int i = tid; i < 1536; i += 128) p2b[i] = u.f.outP[i];
    for (int i = tid; i < 512; i += 128) i2b[i] = u.f.outI[i];
  }
}

// ---------------- level-2 ball conv, batched: 8 targets/block, chunked edge GEMM ----------------
__global__ __launch_bounds__(256, 2) void conv2_kernel(
    const float* __restrict__ pos2, const int* __restrict__ idx2,
    const float* __restrict__ x1,
    const float* __restrict__ w1, const float* __restrict__ b1,
    const float* __restrict__ g, const float* __restrict__ beta,
    const float* __restrict__ m, const float* __restrict__ v,
    const float* __restrict__ w2, const float* __restrict__ b2,
    float* __restrict__ out, float* __restrict__ bout) {
  __shared__ float4 ppos[512];            // cloud coords
  __shared__ unsigned pool[512];          // pooled edges: (t<<16)|j
  __shared__ int cnt[8];
  __shared__ int pcnt;
  __shared__ float4 xjT[128][2];          // staged x_j features [f][s]
  __shared__ float4 hT[256][2];           // h values [k2][s]
  const int b = blockIdx.x >> 6;
  const int grp = blockIdx.x & 63;        // 8 targets: grp*8 .. grp*8+7
  const int c = threadIdx.x;              // 0..255
  const float* pb = pos2 + (size_t)b * 512 * 3;
  if (c < 8) cnt[c] = 0;
  if (c == 0) pcnt = 0;
#pragma unroll
  for (int k = 0; k < 2; ++k) {
    int j = c + (k << 8);
    ppos[j] = make_float4(pb[j * 3 + 0], pb[j * 3 + 1], pb[j * 3 + 2], 0.0f);
  }
  __syncthreads();
  const float rr = (float)(0.25 * 0.25);
#pragma unroll
  for (int t = 0; t < 8; ++t) {
    float4 pi = ppos[(grp << 3) + t];
#pragma unroll
    for (int k = 0; k < 2; ++k) {
      int j = c + (k << 8);
      float4 pj = ppos[j];
      float ddx = __fsub_rn(pi.x, pj.x);
      float ddy = __fsub_rn(pi.y, pj.y);
      float ddz = __fsub_rn(pi.z, pj.z);
      float d2 = __fadd_rn(__fadd_rn(__fmul_rn(ddx, ddx), __fmul_rn(ddy, ddy)),
                           __fmul_rn(ddz, ddz));
      if (d2 <= rr) {
        int s = atomicAdd(&cnt[t], 1);
        if (s < 64) {
          int pe = atomicAdd(&pcnt, 1);
          pool[pe] = ((unsigned)t << 16) | (unsigned)j;
        }
      }
    }
  }
  __syncthreads();
  const int nE = pcnt;
  const float scale = g[c] / sqrtf(v[c] + 1e-5f);
  const float shift = beta[c] - m[c] * scale;
  const float b1c = b1[c];
  const float wr0 = w1[128 * 256 + c], wr1 = w1[129 * 256 + c], wr2 = w1[130 * 256 + c];
  const float b2c0 = b2[c], b2c1 = b2[c + 256];
#define ACCD(i) float A0##i = 0.0f, A1##i = 0.0f;
  REP8(ACCD)
  const int half = c >> 7, cc = c & 127;
  for (int basee = 0; basee < nE; basee += 8) {
    int E0, E1, E2, E3, E4, E5, E6, E7;
#define LOADE(i) E##i = (basee + i < nE) ? (int)pool[basee + i] : -1;
    REP8(LOADE)
#pragma unroll
    for (int rp = 0; rp < 4; ++rp) {
      int r = (rp << 1) + half;
      int er = r == 0 ? E0 : r == 1 ? E1 : r == 2 ? E2 : r == 3 ? E3
             : r == 4 ? E4 : r == 5 ? E5 : r == 6 ? E6 : E7;
      int j = (er >= 0) ? (er & 0xffff) : 0;
      int src = idx2[b * 512 + j];
      ((float*)&xjT[cc][0])[r] = x1[((size_t)b * 1024 + src) * 128 + cc];
    }
    __syncthreads();
#define HDECL(i) float H##i = b1c;
    REP8(HDECL)
#pragma unroll 16
    for (int f = 0; f < 128; ++f) {
      float wf = w1[f * 256 + c];
      float4 xa = xjT[f][0], xb = xjT[f][1];
      H0 = fmaf(xa.x, wf, H0); H1 = fmaf(xa.y, wf, H1);
      H2 = fmaf(xa.z, wf, H2); H3 = fmaf(xa.w, wf, H3);
      H4 = fmaf(xb.x, wf, H4); H5 = fmaf(xb.y, wf, H5);
      H6 = fmaf(xb.z, wf, H6); H7 = fmaf(xb.w, wf, H7);
    }
#define RELBN(i)                                                              \
    {                                                                         \
      int e = E##i;                                                           \
      int jj = (e >= 0) ? (e & 0xffff) : 0;                                   \
      int tt = (e >= 0) ? (e >> 16) : 0;                                      \
      float4 pj = ppos[jj];                                                   \
      float4 pi = ppos[(grp << 3) + tt];                                      \
      H##i = fmaf(pj.x - pi.x, wr0, H##i);                                    \
      H##i = fmaf(pj.y - pi.y, wr1, H##i);                                    \
      H##i = fmaf(pj.z - pi.z, wr2, H##i);                                    \
      H##i = fmaxf(fmaf(H##i, scale, shift), 0.0f);                           \
    }
    REP8(RELBN)
    hT[c][0] = make_float4(H0, H1, H2, H3);
    hT[c][1] = make_float4(H4, H5, H6, H7);
    __syncthreads();
#define ODECL(i) float O0##i = 0.0f, O1##i = 0.0f;
    REP8(ODECL)
#pragma unroll 8
    for (int k2 = 0; k2 < 256; ++k2) {
      float w2a = w2[k2 * 512 + c];
      float w2b = w2[k2 * 512 + c + 256];
      float4 ha = hT[k2][0], hb = hT[k2][1];
      O00 = fmaf(ha.x, w2a, O00); O10 = fmaf(ha.x, w2b, O10);
      O01 = fmaf(ha.y, w2a, O01); O11 = fmaf(ha.y, w2b, O11);
      O02 = fmaf(ha.z, w2a, O02); O12 = fmaf(ha.z, w2b, O12);
      O03 = fmaf(ha.w, w2a, O03); O13 = fmaf(ha.w, w2b, O13);
      O04 = fmaf(hb.x, w2a, O04); O14 = fmaf(hb.x, w2b, O14);
      O05 = fmaf(hb.y, w2a, O05); O15 = fmaf(hb.y, w2b, O15);
      O06 = fmaf(hb.z, w2a, O06); O16 = fmaf(hb.z, w2b, O16);
      O07 = fmaf(hb.w, w2a, O07); O17 = fmaf(hb.w, w2b, O17);
    }
#define MERGEE(i)                                                             \
    if (E##i >= 0) {                                                          \
      int tt = E##i >> 16;                                                    \
      float m0 = fmaxf(__fadd_rn(O0##i, b2c0), 0.0f);                         \
      float m1 = fmaxf(__fadd_rn(O1##i, b2c1), 0.0f);                         \
      if (tt == 0) { A00 = fmaxf(A00, m0); A10 = fmaxf(A10, m1); }            \
      else if (tt == 1) { A01 = fmaxf(A01, m0); A11 = fmaxf(A11, m1); }       \
      else if (tt == 2) { A02 = fmaxf(A02, m0); A12 = fmaxf(A12, m1); }       \
      else if (tt == 3) { A03 = fmaxf(A03, m0); A13 = fmaxf(A13, m1); }       \
      else if (tt == 4) { A04 = fmaxf(A04, m0); A14 = fmaxf(A14, m1); }       \
      else if (tt == 5) { A05 = fmaxf(A05, m0); A15 = fmaxf(A15, m1); }       \
      else { A06 = (tt == 6) ? fmaxf(A06, m0) : A06;                          \
             A16 = (tt == 6) ? fmaxf(A16, m1) : A16;                          \
             A07 = (tt == 7) ? fmaxf(A07, m0) : A07;                          \
             A17 = (tt == 7) ? fmaxf(A17, m1) : A17; }                        \
    }
    REP8(MERGEE)
  }
#define WROUT(i)                                                              \
  {                                                                           \
    float* ob = out + ((size_t)(b * 512 + (grp << 3) + i)) * 512;             \
    ob[c] = A0##i;                                                            \
    ob[c + 256] = A1##i;                                                      \
  }
  REP8(WROUT)
  if (c < 8) bout[b * 512 + (grp << 3) + c] = (float)b;  // batch ids as f32
}

extern "C" void kernel_launch(void* const* d_in, const int* in_sizes, int n_in,
                              void* d_out, int out_size, void* d_ws, size_t ws_size,
                              hipStream_t stream) {
  const float* pos    = (const float*)d_in[0];
  const float* c1_w1  = (const float*)d_in[1];
  const float* c1_b1  = (const float*)d_in[2];
  const float* c1_g   = (const float*)d_in[3];
  const float* c1_be  = (const float*)d_in[4];
  const float* c1_m   = (const float*)d_in[5];
  const float* c1_v   = (const float*)d_in[6];
  const float* c1_w2  = (const float*)d_in[7];
  const float* c1_b2  = (const float*)d_in[8];
  const float* c2_w1  = (const float*)d_in[9];
  const float* c2_b1  = (const float*)d_in[10];
  const float* c2_g   = (const float*)d_in[11];
  const float* c2_be  = (const float*)d_in[12];
  const float* c2_m   = (const float*)d_in[13];
  const float* c2_v   = (const float*)d_in[14];
  const float* c2_w2  = (const float*)d_in[15];
  const float* c2_b2  = (const float*)d_in[16];

  char* ws = (char*)d_ws;
  float* pos1 = (float*)(ws + 0);        // 8*1024*3*4 =  98304
  int*   idx2 = (int*)  (ws + 98304);    // 8*512*4    =  16384
  float* pos2 = (float*)(ws + 114688);   // 8*512*3*4  =  49152
  float* x1   = (float*)(ws + 163840);   // 8*1024*128*4 = 4194304 (end 4358144)
  float* out  = (float*)d_out;

  norm_fps1_kernel<<<8, 256, 0, stream>>>(pos, pos1);
  mid_kernel<<<8 + 8192, 128, 0, stream>>>(pos1, c1_w1, c1_b1, c1_g, c1_be,
                                           c1_m, c1_v, c1_w2, c1_b2, x1, idx2, pos2);
  conv2_kernel<<<512, 256, 0, stream>>>(pos2, idx2, x1, c2_w1, c2_b1, c2_g,
                                        c2_be, c2_m, c2_v, c2_w2, c2_b2, out,
                                        out + 2097152);
}

// Round 10
// 793.403 us; speedup vs baseline: 1.1736x; 1.1736x over previous
//
#include <hip/hip_runtime.h>

#define B_ 8
#define N_ 2048

#define REP8(M) M(0) M(1) M(2) M(3) M(4) M(5) M(6) M(7)
#define REP4(M) M(0) M(1) M(2) M(3)

// one DPP max step: lanes without a source contribute -1.0f (identity; dists >= 0)
template <int CTRL>
__device__ __forceinline__ float dppMaxStep(float v) {
  int o = __builtin_amdgcn_update_dpp(__float_as_int(-1.0f), __float_as_int(v),
                                      CTRL, 0xF, 0xF, false);
  return fmaxf(v, __int_as_float(o));
}

__device__ __forceinline__ float waveMax(float v) {
  v = dppMaxStep<0x111>(v);  // row_shr:1
  v = dppMaxStep<0x112>(v);  // row_shr:2
  v = dppMaxStep<0x114>(v);  // row_shr:4
  v = dppMaxStep<0x118>(v);  // row_shr:8
  v = dppMaxStep<0x142>(v);  // row_bcast:15
  v = dppMaxStep<0x143>(v);  // row_bcast:31  -> lane 63 holds wave max
  return v;
}

#define DECL8(i) float X##i, Y##i, Z##i, D##i;

// distance update: bit-exact ((dx*dx+dy*dy)+dz*dz), fminf
#define UPD8(i)                                                               \
  {                                                                           \
    float ddx = __fsub_rn(X##i, qx);                                          \
    float ddy = __fsub_rn(Y##i, qy);                                          \
    float ddz = __fsub_rn(Z##i, qz);                                          \
    float d = __fadd_rn(__fadd_rn(__fmul_rn(ddx, ddx), __fmul_rn(ddy, ddy)),  \
                        __fmul_rn(ddz, ddz));                                 \
    D##i = fminf(D##i, d);                                                    \
  }

// in-lane argmax tree (global indices); strict > ascending keeps smallest index on tie
#define LANE_TREE8V                                                           \
  float v01 = (D1 > D0) ? D1 : D0;  int g01 = (D1 > D0) ? gbase + 1 : gbase;  \
  float v23 = (D3 > D2) ? D3 : D2;  int g23 = (D3 > D2) ? gbase + 3 : gbase + 2; \
  float v45 = (D5 > D4) ? D5 : D4;  int g45 = (D5 > D4) ? gbase + 5 : gbase + 4; \
  float v67 = (D7 > D6) ? D7 : D6;  int g67 = (D7 > D6) ? gbase + 7 : gbase + 6; \
  float v03 = (v23 > v01) ? v23 : v01;  int g03 = (v23 > v01) ? g23 : g01;    \
  float v47 = (v67 > v45) ? v67 : v45;  int g47 = (v67 > v45) ? g67 : g45;    \
  float bv  = (v47 > v03) ? v47 : v03;  int bg  = (v47 > v03) ? g47 : g03;

// ---------------- fused normalize (f64 stats, fp32 ops match np) + FPS 2048->1024 ----------------
// R8's measured-best loop, byte-identical (R9's owner-mux variant regressed +200 cyc/iter).
__global__ __launch_bounds__(256) void norm_fps1_kernel(const float* __restrict__ pos,
                                                        float* __restrict__ pos1) {
  __shared__ float4 Sp[2048];     // normalized points (padded) for winner lookup
  __shared__ float outP[1024 * 3];// selected points, flushed at end
  __shared__ float2 red[2][4];    // double-buffered per-wave (max, idx) slots
  __shared__ double wsum[3][4];
  __shared__ float bc[6];
  const int b = blockIdx.x, tid = threadIdx.x;
  const float* base = pos + (size_t)b * N_ * 3;
  float px[8], py[8], pz[8];
  double sx = 0.0, sy = 0.0, sz = 0.0;
#pragma unroll
  for (int k = 0; k < 8; ++k) {
    int g = tid * 8 + k;
    px[k] = base[g * 3 + 0];
    py[k] = base[g * 3 + 1];
    pz[k] = base[g * 3 + 2];
    sx += (double)px[k]; sy += (double)py[k]; sz += (double)pz[k];
  }
  const int wid = tid >> 6, lid = tid & 63;
#pragma unroll
  for (int off = 32; off >= 1; off >>= 1) {
    sx += __shfl_down(sx, off);
    sy += __shfl_down(sy, off);
    sz += __shfl_down(sz, off);
  }
  if (lid == 0) { wsum[0][wid] = sx; wsum[1][wid] = sy; wsum[2][wid] = sz; }
  __syncthreads();
  if (tid == 0) {
    bc[0] = (float)((wsum[0][0] + wsum[0][1] + wsum[0][2] + wsum[0][3]) / 2048.0);
    bc[1] = (float)((wsum[1][0] + wsum[1][1] + wsum[1][2] + wsum[1][3]) / 2048.0);
    bc[2] = (float)((wsum[2][0] + wsum[2][1] + wsum[2][2] + wsum[2][3]) / 2048.0);
  }
  __syncthreads();
  const float mx = bc[0], my = bc[1], mz = bc[2];
  float dxa[8], dya[8], dza[8];
  double qxs = 0.0, qys = 0.0, qzs = 0.0;
#pragma unroll
  for (int k = 0; k < 8; ++k) {
    dxa[k] = __fsub_rn(px[k], mx);
    dya[k] = __fsub_rn(py[k], my);
    dza[k] = __fsub_rn(pz[k], mz);
    qxs += (double)__fmul_rn(dxa[k], dxa[k]);
    qys += (double)__fmul_rn(dya[k], dya[k]);
    qzs += (double)__fmul_rn(dza[k], dza[k]);
  }
#pragma unroll
  for (int off = 32; off >= 1; off >>= 1) {
    qxs += __shfl_down(qxs, off);
    qys += __shfl_down(qys, off);
    qzs += __shfl_down(qzs, off);
  }
  if (lid == 0) { wsum[0][wid] = qxs; wsum[1][wid] = qys; wsum[2][wid] = qzs; }
  __syncthreads();
  if (tid == 0) {
    bc[3] = __fadd_rn(__fsqrt_rn((float)((wsum[0][0]+wsum[0][1]+wsum[0][2]+wsum[0][3]) / 2047.0)), 1e-6f);
    bc[4] = __fadd_rn(__fsqrt_rn((float)((wsum[1][0]+wsum[1][1]+wsum[1][2]+wsum[1][3]) / 2047.0)), 1e-6f);
    bc[5] = __fadd_rn(__fsqrt_rn((float)((wsum[2][0]+wsum[2][1]+wsum[2][2]+wsum[2][3]) / 2047.0)), 1e-6f);
  }
  __syncthreads();
  const float isx = bc[3], isy = bc[4], isz = bc[5];
  REP8(DECL8)
#define INIT8(i)                                                              \
  {                                                                           \
    X##i = __fdiv_rn(dxa[i], isx);                                            \
    Y##i = __fdiv_rn(dya[i], isy);                                            \
    Z##i = __fdiv_rn(dza[i], isz);                                            \
    D##i = 1e10f;                                                             \
    Sp[tid * 8 + i] = make_float4(X##i, Y##i, Z##i, 0.0f);                    \
  }
  REP8(INIT8)
  __syncthreads();
  float4 q0 = Sp[0];  // deterministic FPS start at index 0 (LDS broadcast)
  float qx = q0.x, qy = q0.y, qz = q0.z;
  if (tid == 0) { outP[0] = qx; outP[1] = qy; outP[2] = qz; }
  const int gbase = tid * 8;
  for (int t = 1; t < 1024; ++t) {
    REP8(UPD8)
    LANE_TREE8V
    // wave max (value only), then locate owner: lowest lane with bv==vmax = smallest index
    float mv = waveMax(bv);
    float vmax = __int_as_float(__builtin_amdgcn_readlane(__float_as_int(mv), 63));
    unsigned long long msk = __ballot(bv == vmax);
    int owner = __builtin_ctzll(msk);
    int gw = __builtin_amdgcn_readlane(bg, owner);
    const int par = t & 1;
    if (lid == 0) red[par][wid] = make_float2(vmax, __int_as_float(gw));
    __syncthreads();
    float2 r0 = red[par][0], r1 = red[par][1], r2 = red[par][2], r3 = red[par][3];
    float fv = r0.x; int fg = __float_as_int(r0.y);
    if (r1.x > fv) { fv = r1.x; fg = __float_as_int(r1.y); }
    if (r2.x > fv) { fv = r2.x; fg = __float_as_int(r2.y); }
    if (r3.x > fv) { fv = r3.x; fg = __float_as_int(r3.y); }
    float4 pw = Sp[fg];  // uniform index -> LDS broadcast
    qx = pw.x; qy = pw.y; qz = pw.z;
    if (tid == 0) { outP[t * 3 + 0] = qx; outP[t * 3 + 1] = qy; outP[t * 3 + 2] = qz; }
  }
  __syncthreads();
  float* p1b = pos1 + (size_t)b * 1024 * 3;
  for (int i = tid; i < 3072; i += 256) p1b[i] = outP[i];
}

// ---------------- mid (256 threads): fps2 4-wave (blocks 0..7) + conv1 (blocks 8..8199) ----------
__global__ __launch_bounds__(256) void mid_kernel(
    const float* __restrict__ pos1,
    const float* __restrict__ w1, const float* __restrict__ b1,
    const float* __restrict__ g, const float* __restrict__ beta,
    const float* __restrict__ m, const float* __restrict__ v,
    const float* __restrict__ w2, const float* __restrict__ b2,
    float* __restrict__ x1out,
    int* __restrict__ idx2, float* __restrict__ pos2) {
  __shared__ union MidU {
    struct { int nbr[64]; int cnt; float hbuf[128]; } c;
    struct { float4 Sp2[1024]; float2 red2[2][4]; float outP[512 * 3]; int outI[512]; } f;
  } u;
  if (blockIdx.x >= 8) {
    // ---- conv1: one block per target point; 256 threads scan, 128 run the MLP ----
    const int bb = blockIdx.x - 8;
    const int b = bb >> 10;
    const int i = bb & 1023;
    const int c = threadIdx.x;           // 0..255
    const int ch = c & 127;              // channel id (params have 128 entries)
    const float* pb = pos1 + (size_t)b * 1024 * 3;
    const float xi = pb[i * 3 + 0], yi = pb[i * 3 + 1], zi = pb[i * 3 + 2];
    if (c == 0) u.c.cnt = 0;
    __syncthreads();
    const float rr = (float)(0.1 * 0.1);  // matches weak-typed r*r rounding
#pragma unroll
    for (int k = 0; k < 4; ++k) {
      int j = c + (k << 8);
      float ddx = __fsub_rn(xi, pb[j * 3 + 0]);
      float ddy = __fsub_rn(yi, pb[j * 3 + 1]);
      float ddz = __fsub_rn(zi, pb[j * 3 + 2]);
      float d2 = __fadd_rn(__fadd_rn(__fmul_rn(ddx, ddx), __fmul_rn(ddy, ddy)),
                           __fmul_rn(ddz, ddz));
      if (d2 <= rr) {
        int s = atomicAdd(&u.c.cnt, 1);
        if (s < 64) u.c.nbr[s] = j;
      }
    }
    __syncthreads();
    const int n = min(u.c.cnt, 64);
    const float scale = g[ch] / sqrtf(v[ch] + 1e-5f);
    const float shift = beta[ch] - m[ch] * scale;
    float w1c[6];
#pragma unroll
    for (int f = 0; f < 6; ++f) w1c[f] = w1[f * 128 + ch];
    const float b1c = b1[ch], b2c = b2[ch];
    float acc = 0.0f;  // relu >= 0 and self always valid
    for (int qq = 0; qq < n; ++qq) {
      const int j = u.c.nbr[qq];
      if (c < 128) {
        const float fx = pb[j * 3 + 0], fy = pb[j * 3 + 1], fz = pb[j * 3 + 2];
        float h = b1c;
        h = fmaf(fx, w1c[0], h);
        h = fmaf(fy, w1c[1], h);
        h = fmaf(fz, w1c[2], h);
        h = fmaf(fx - xi, w1c[3], h);
        h = fmaf(fy - yi, w1c[4], h);
        h = fmaf(fz - zi, w1c[5], h);
        h = fmaxf(fmaf(h, scale, shift), 0.0f);
        u.c.hbuf[c] = h;
      }
      __syncthreads();
      if (c < 128) {
        float o = b2c;
#pragma unroll 8
        for (int k2 = 0; k2 < 128; ++k2) o = fmaf(u.c.hbuf[k2], w2[(k2 << 7) + c], o);
        acc = fmaxf(acc, fmaxf(o, 0.0f));
      }
      __syncthreads();
    }
    if (c < 128) x1out[((size_t)(b * 1024 + i)) * 128 + c] = acc;
  } else {
    // ---- fps2: 1024 -> 512, 4 waves, 4 pts/thread (R8 loop structure, wider) ----
    const int b = blockIdx.x;
    const int tid = threadIdx.x;
    const int wid = tid >> 6, lid = tid & 63;
    const float* p1b = pos1 + (size_t)b * 1024 * 3;
    float X0, Y0, Z0, D0, X1, Y1, Z1, D1, X2, Y2, Z2, D2, X3, Y3, Z3, D3;
#define LOADF4(i)                                                             \
    {                                                                         \
      const float* pp = p1b + (tid * 4 + i) * 3;                              \
      X##i = pp[0]; Y##i = pp[1]; Z##i = pp[2];                               \
      D##i = 1e10f;                                                           \
      u.f.Sp2[tid * 4 + i] = make_float4(X##i, Y##i, Z##i, 0.0f);             \
    }
    REP4(LOADF4)
    __syncthreads();
    float4 q0 = u.f.Sp2[0];
    float qx = q0.x, qy = q0.y, qz = q0.z;
    if (tid == 0) {
      u.f.outP[0] = qx; u.f.outP[1] = qy; u.f.outP[2] = qz;
      u.f.outI[0] = 0;
    }
    const int gbase = tid * 4;
    for (int t = 1; t < 512; ++t) {
      REP4(UPD8)
      float v01 = (D1 > D0) ? D1 : D0;  int g01 = (D1 > D0) ? gbase + 1 : gbase;
      float v23 = (D3 > D2) ? D3 : D2;  int g23 = (D3 > D2) ? gbase + 3 : gbase + 2;
      float bv  = (v23 > v01) ? v23 : v01;  int bg = (v23 > v01) ? g23 : g01;
      float mv = waveMax(bv);
      float vmax = __int_as_float(__builtin_amdgcn_readlane(__float_as_int(mv), 63));
      unsigned long long msk = __ballot(bv == vmax);
      int owner = __builtin_ctzll(msk);
      int gw = __builtin_amdgcn_readlane(bg, owner);
      const int par = t & 1;
      if (lid == 0) u.f.red2[par][wid] = make_float2(vmax, __int_as_float(gw));
      __syncthreads();
      float2 r0 = u.f.red2[par][0], r1 = u.f.red2[par][1];
      float2 r2 = u.f.red2[par][2], r3 = u.f.red2[par][3];
      float fv = r0.x; int fg = __float_as_int(r0.y);
      if (r1.x > fv) { fv = r1.x; fg = __float_as_int(r1.y); }
      if (r2.x > fv) { fv = r2.x; fg = __float_as_int(r2.y); }
      if (r3.x > fv) { fv = r3.x; fg = __float_as_int(r3.y); }
      float4 pw = u.f.Sp2[fg];
      qx = pw.x; qy = pw.y; qz = pw.z;
      if (tid == 0) {
        u.f.outP[t * 3 + 0] = qx; u.f.outP[t * 3 + 1] = qy; u.f.outP[t * 3 + 2] = qz;
        u.f.outI[t] = fg;
      }
    }
    __syncthreads();
    float* p2b = pos2 + (size_t)b * 512 * 3;
    int* i2b = idx2 + b * 512;
    for (int i = tid; i < 1536; i += 256) p2b[i] = u.f.outP[i];
    for (int i = tid; i < 512; i += 256) i2b[i] = u.f.outI[i];
  }
}

// ---------------- level-2 ball conv, batched: 8 targets/block, chunked edge GEMM ----------------
__global__ __launch_bounds__(256, 2) void conv2_kernel(
    const float* __restrict__ pos2, const int* __restrict__ idx2,
    const float* __restrict__ x1,
    const float* __restrict__ w1, const float* __restrict__ b1,
    const float* __restrict__ g, const float* __restrict__ beta,
    const float* __restrict__ m, const float* __restrict__ v,
    const float* __restrict__ w2, const float* __restrict__ b2,
    float* __restrict__ out, float* __restrict__ bout) {
  __shared__ float4 ppos[512];            // cloud coords
  __shared__ unsigned pool[512];          // pooled edges: (t<<16)|j
  __shared__ int cnt[8];
  __shared__ int pcnt;
  __shared__ float4 xjT[128][2];          // staged x_j features [f][s]
  __shared__ float4 hT[256][2];           // h values [k2][s]
  const int b = blockIdx.x >> 6;
  const int grp = blockIdx.x & 63;        // 8 targets: grp*8 .. grp*8+7
  const int c = threadIdx.x;              // 0..255
  const float* pb = pos2 + (size_t)b * 512 * 3;
  if (c < 8) cnt[c] = 0;
  if (c == 0) pcnt = 0;
#pragma unroll
  for (int k = 0; k < 2; ++k) {
    int j = c + (k << 8);
    ppos[j] = make_float4(pb[j * 3 + 0], pb[j * 3 + 1], pb[j * 3 + 2], 0.0f);
  }
  __syncthreads();
  const float rr = (float)(0.25 * 0.25);
#pragma unroll
  for (int t = 0; t < 8; ++t) {
    float4 pi = ppos[(grp << 3) + t];
#pragma unroll
    for (int k = 0; k < 2; ++k) {
      int j = c + (k << 8);
      float4 pj = ppos[j];
      float ddx = __fsub_rn(pi.x, pj.x);
      float ddy = __fsub_rn(pi.y, pj.y);
      float ddz = __fsub_rn(pi.z, pj.z);
      float d2 = __fadd_rn(__fadd_rn(__fmul_rn(ddx, ddx), __fmul_rn(ddy, ddy)),
                           __fmul_rn(ddz, ddz));
      if (d2 <= rr) {
        int s = atomicAdd(&cnt[t], 1);
        if (s < 64) {
          int pe = atomicAdd(&pcnt, 1);
          pool[pe] = ((unsigned)t << 16) | (unsigned)j;
        }
      }
    }
  }
  __syncthreads();
  const int nE = pcnt;
  const float scale = g[c] / sqrtf(v[c] + 1e-5f);
  const float shift = beta[c] - m[c] * scale;
  const float b1c = b1[c];
  const float wr0 = w1[128 * 256 + c], wr1 = w1[129 * 256 + c], wr2 = w1[130 * 256 + c];
  const float b2c0 = b2[c], b2c1 = b2[c + 256];
#define ACCD(i) float A0##i = 0.0f, A1##i = 0.0f;
  REP8(ACCD)
  const int half = c >> 7, cc = c & 127;
  for (int basee = 0; basee < nE; basee += 8) {
    int E0, E1, E2, E3, E4, E5, E6, E7;
#define LOADE(i) E##i = (basee + i < nE) ? (int)pool[basee + i] : -1;
    REP8(LOADE)
#pragma unroll
    for (int rp = 0; rp < 4; ++rp) {
      int r = (rp << 1) + half;
      int er = r == 0 ? E0 : r == 1 ? E1 : r == 2 ? E2 : r == 3 ? E3
             : r == 4 ? E4 : r == 5 ? E5 : r == 6 ? E6 : E7;
      int j = (er >= 0) ? (er & 0xffff) : 0;
      int src = idx2[b * 512 + j];
      ((float*)&xjT[cc][0])[r] = x1[((size_t)b * 1024 + src) * 128 + cc];
    }
    __syncthreads();
#define HDECL(i) float H##i = b1c;
    REP8(HDECL)
#pragma unroll 16
    for (int f = 0; f < 128; ++f) {
      float wf = w1[f * 256 + c];
      float4 xa = xjT[f][0], xb = xjT[f][1];
      H0 = fmaf(xa.x, wf, H0); H1 = fmaf(xa.y, wf, H1);
      H2 = fmaf(xa.z, wf, H2); H3 = fmaf(xa.w, wf, H3);
      H4 = fmaf(xb.x, wf, H4); H5 = fmaf(xb.y, wf, H5);
      H6 = fmaf(xb.z, wf, H6); H7 = fmaf(xb.w, wf, H7);
    }
#define RELBN(i)                                                              \
    {                                                                         \
      int e = E##i;                                                           \
      int jj = (e >= 0) ? (e & 0xffff) : 0;                                   \
      int tt = (e >= 0) ? (e >> 16) : 0;                                      \
      float4 pj = ppos[jj];                                                   \
      float4 pi = ppos[(grp << 3) + tt];                                      \
      H##i = fmaf(pj.x - pi.x, wr0, H##i);                                    \
      H##i = fmaf(pj.y - pi.y, wr1, H##i);                                    \
      H##i = fmaf(pj.z - pi.z, wr2, H##i);                                    \
      H##i = fmaxf(fmaf(H##i, scale, shift), 0.0f);                           \
    }
    REP8(RELBN)
    hT[c][0] = make_float4(H0, H1, H2, H3);
    hT[c][1] = make_float4(H4, H5, H6, H7);
    __syncthreads();
#define ODECL(i) float O0##i = 0.0f, O1##i = 0.0f;
    REP8(ODECL)
#pragma unroll 8
    for (int k2 = 0; k2 < 256; ++k2) {
      float w2a = w2[k2 * 512 + c];
      float w2b = w2[k2 * 512 + c + 256];
      float4 ha = hT[k2][0], hb = hT[k2][1];
      O00 = fmaf(ha.x, w2a, O00); O10 = fmaf(ha.x, w2b, O10);
      O01 = fmaf(ha.y, w2a, O01); O11 = fmaf(ha.y, w2b, O11);
      O02 = fmaf(ha.z, w2a, O02); O12 = fmaf(ha.z, w2b, O12);
      O03 = fmaf(ha.w, w2a, O03); O13 = fmaf(ha.w, w2b, O13);
      O04 = fmaf(hb.x, w2a, O04); O14 = fmaf(hb.x, w2b, O14);
      O05 = fmaf(hb.y, w2a, O05); O15 = fmaf(hb.y, w2b, O15);
      O06 = fmaf(hb.z, w2a, O06); O16 = fmaf(hb.z, w2b, O16);
      O07 = fmaf(hb.w, w2a, O07); O17 = fmaf(hb.w, w2b, O17);
    }
#define MERGEE(i)                                                             \
    if (E##i >= 0) {                                                          \
      int tt = E##i >> 16;                                                    \
      float m0 = fmaxf(__fadd_rn(O0##i, b2c0), 0.0f);                         \
      float m1 = fmaxf(__fadd_rn(O1##i, b2c1), 0.0f);                         \
      if (tt == 0) { A00 = fmaxf(A00, m0); A10 = fmaxf(A10, m1); }            \
      else if (tt == 1) { A01 = fmaxf(A01, m0); A11 = fmaxf(A11, m1); }       \
      else if (tt == 2) { A02 = fmaxf(A02, m0); A12 = fmaxf(A12, m1); }       \
      else if (tt == 3) { A03 = fmaxf(A03, m0); A13 = fmaxf(A13, m1); }       \
      else if (tt == 4) { A04 = fmaxf(A04, m0); A14 = fmaxf(A14, m1); }       \
      else if (tt == 5) { A05 = fmaxf(A05, m0); A15 = fmaxf(A15, m1); }       \
      else { A06 = (tt == 6) ? fmaxf(A06, m0) : A06;                          \
             A16 = (tt == 6) ? fmaxf(A16, m1) : A16;                          \
             A07 = (tt == 7) ? fmaxf(A07, m0) : A07;                          \
             A17 = (tt == 7) ? fmaxf(A17, m1) : A17; }                        \
    }
    REP8(MERGEE)
  }
#define WROUT(i)                                                              \
  {                                                                           \
    float* ob = out + ((size_t)(b * 512 + (grp << 3) + i)) * 512;             \
    ob[c] = A0##i;                                                            \
    ob[c + 256] = A1##i;                                                      \
  }
  REP8(WROUT)
  if (c < 8) bout[b * 512 + (grp << 3) + c] = (float)b;  // batch ids as f32
}

extern "C" void kernel_launch(void* const* d_in, const int* in_sizes, int n_in,
                              void* d_out, int out_size, void* d_ws, size_t ws_size,
                              hipStream_t stream) {
  const float* pos    = (const float*)d_in[0];
  const float* c1_w1  = (const float*)d_in[1];
  const float* c1_b1  = (const float*)d_in[2];
  const float* c1_g   = (const float*)d_in[3];
  const float* c1_be  = (const float*)d_in[4];
  const float* c1_m   = (const float*)d_in[5];
  const float* c1_v   = (const float*)d_in[6];
  const float* c1_w2  = (const float*)d_in[7];
  const float* c1_b2  = (const float*)d_in[8];
  const float* c2_w1  = (const float*)d_in[9];
  const float* c2_b1  = (const float*)d_in[10];
  const float* c2_g   = (const float*)d_in[11];
  const float* c2_be  = (const float*)d_in[12];
  const float* c2_m   = (const float*)d_in[13];
  const float* c2_v   = (const float*)d_in[14];
  const float* c2_w2  = (const float*)d_in[15];
  const float* c2_b2  = (const float*)d_in[16];

  char* ws = (char*)d_ws;
  float* pos1 = (float*)(ws + 0);        // 8*1024*3*4 =  98304
  int*   idx2 = (int*)  (ws + 98304);    // 8*512*4    =  16384
  float* pos2 = (float*)(ws + 114688);   // 8*512*3*4  =  49152
  float* x1   = (float*)(ws + 163840);   // 8*1024*128*4 = 4194304 (end 4358144)
  float* out  = (float*)d_out;

  norm_fps1_kernel<<<8, 256, 0, stream>>>(pos, pos1);
  mid_kernel<<<8 + 8192, 256, 0, stream>>>(pos1, c1_w1, c1_b1, c1_g, c1_be,
                                           c1_m, c1_v, c1_w2, c1_b2, x1, idx2, pos2);
  conv2_kernel<<<512, 256, 0, stream>>>(pos2, idx2, x1, c2_w1, c2_b1, c2_g,
                                        c2_be, c2_m, c2_v, c2_w2, c2_b2, out,
                                        out + 2097152);
}